// Round 10
// baseline (1026.382 us; speedup 1.0000x reference)
//
#include <hip/hip_runtime.h>

// MyRNN: B=128, T=80, E=100, V=10000, U=512
// 8 clusters x 32 member-blocks, formed dynamically by physical XCD
// (s_getreg HW_REG_XCC_ID + agent-scope slot grab): ~132KB LDS -> 1 block/CU,
// grid 256 fills all CUs -> cluster members share one XCD L2 BY CONSTRUCTION
// (R7-proven). Cluster c owns batch rows [16c,16c+16); member m owns cols
// [16m,16m+16) of rk0/rk1/k1 (stationary in LDS, hi/lo bf16 split).
// Ladder: R1 3.9ms -> R4 921us (batched MALL) -> R7 781us (exchange data in
// XCD L2: plain stores + sc0 dwordx4 loads; WRITE_SIZE 42->2MB proved it).
// R8 hang: un-scoped atomic sync = unverified routing. R9 compile fail:
// tied struct asm operands. R10 = R7 skeleton (tid0 poll of MALL counter +
// __syncthreads; 64 posts/step) with:
//  (a) h/h0 stored as hi/lo bf16 PLANES; MFMA A-fragments loaded DIRECTLY
//      from XCD L2 (sc0 dwordx4) -> no gather/LDS-stage/unpack phase;
//  (b) mid-step __syncthreads before wave0's post certifies ALL blocks'
//      rk0/rk1 reads of h(t-1) before anyone writes h(t) (closes the race
//      a barrier-free scheme would have);
//  (c) wave0 prefetches emb(t+1) into double-buffered sE during round B
//      (self-consumed LDS -> no extra barrier).

typedef __attribute__((ext_vector_type(8))) short short8;
typedef __attribute__((ext_vector_type(4))) float f32x4;

#define MFMA16(a,b,c) __builtin_amdgcn_mfma_f32_16x16x32_bf16(a,b,c,0,0,0)
#define LOAD_RLX(p)    __hip_atomic_load((p), __ATOMIC_RELAXED, __HIP_MEMORY_SCOPE_AGENT)
#define ADD_RLX(p,v)   __hip_atomic_fetch_add((p), (v), __ATOMIC_RELAXED, __HIP_MEMORY_SCOPE_AGENT)
#define L2LOADX4(dst, addr) \
  asm volatile("global_load_dwordx4 %0, %1, off sc0" : "=v"(dst) : "v"(addr))
#define WAIT_VM0() asm volatile("s_waitcnt vmcnt(0)" ::: "memory")

union U16x8 { uint4 u; short8 s; };

__device__ __forceinline__ short f2bf(float v){
  unsigned u = __float_as_uint(v);
  u = (u + 0x7fffu + ((u >> 16) & 1u)) >> 16;   // RNE to bf16
  return (short)u;
}
__device__ __forceinline__ float bf2f(short s){
  return __uint_as_float(((unsigned)(unsigned short)s) << 16);
}
__device__ __forceinline__ float fast_tanh(float x){
  x = fminf(15.f, fmaxf(-15.f, x));
  float e = __expf(2.f * x);
  return (e - 1.f) * __builtin_amdgcn_rcpf(e + 1.f);
}

__launch_bounds__(128, 1)
__global__ void rnn_kernel(const int* __restrict__ tokens,
                           const float* __restrict__ emb,
                           const float* __restrict__ k0,
                           const float* __restrict__ rk0,
                           const float* __restrict__ b0,
                           const float* __restrict__ k1,
                           const float* __restrict__ rk1,
                           const float* __restrict__ b1,
                           const float* __restrict__ wd,
                           const float* __restrict__ bd,
                           float* __restrict__ out,
                           char* __restrict__ ws)
{
  constexpr int T = 80, E = 100, U = 512;
  const int tid  = threadIdx.x;
  const int w    = tid >> 6;          // wave id (0/1)
  const int lane = tid & 63;
  const int m    = lane & 15;         // row (A) / col (B,C)
  const int q    = lane >> 4;         // quad 0..3

  __shared__ __align__(16) short sW[6][16][520];    // rk0 hi/lo, rk1 hi/lo, k1 hi/lo : [col][k]
  __shared__ __align__(16) short sE[2][2][16][136]; // emb dbuf [buf][hi/lo][row][e] (pad->128)
  __shared__ __align__(16) short sK0[2][16][136];   // k0 slice hi,lo : [col][k] (padded)
  __shared__ int   sTok[16][80];
  __shared__ float sB0[16], sB1[16];
  __shared__ float sRed[16][8];
  __shared__ int   sReg[2];

  int*   cnts   = (int*)ws;                    // 8 counters, 64B stride (MALL, memset 0)
  int*   regCnt = (int*)(ws + 512);            // 8 registration counters (MALL, memset 0)
  short* hHi  = (short*)(ws + 16*1024);        // h1 hi plane [128][512]
  short* hLo  = hHi  + 128*U;
  short* h0Hi = hLo  + 128*U;                  // h0 planes
  short* h0Lo = h0Hi + 128*U;

  // -------- dynamic cluster formation: cluster id = physical XCD --------
  int xcc;
  asm volatile("s_getreg_b32 %0, hwreg(HW_REG_XCC_ID)" : "=s"(xcc));
  if (tid == 0){
    int slot = ADD_RLX(regCnt + (xcc & 7)*16, 1);   // 0..31 within this XCD
    sReg[0] = xcc & 7;
    sReg[1] = slot;
  }
  __syncthreads();
  const int cl  = sReg[0];
  const int mem = sReg[1];
  int* cnt = cnts + cl*16;

  // ---------------- prologue: stationary weights -> LDS ----------------
  const float* mats[3] = { rk0, rk1, k1 };
  for (int mi = 0; mi < 3; ++mi){
    const float* G = mats[mi];
    for (int i = tid; i < 16*U; i += 128){
      int k = i >> 4, c = i & 15;
      float v  = G[k*U + mem*16 + c];
      short hi = f2bf(v);
      short lo = f2bf(v - bf2f(hi));
      sW[2*mi+0][c][k] = hi;
      sW[2*mi+1][c][k] = lo;
    }
  }
  for (int i = tid; i < 2*2*16*136; i += 128) ((short*)sE)[i] = 0;
  for (int i = tid; i < 2*16*136;   i += 128) ((short*)sK0)[i] = 0;
  __syncthreads();
  for (int i = tid; i < 16*E; i += 128){
    int e = i >> 4, c = i & 15;
    float v  = k0[e*U + mem*16 + c];
    short hi = f2bf(v);
    short lo = f2bf(v - bf2f(hi));
    sK0[0][c][e] = hi; sK0[1][c][e] = lo;
  }
  for (int i = tid; i < 16*T; i += 128){
    int r = i / T, t = i - r*T;
    sTok[r][t] = tokens[(cl*16 + r)*T + t];
  }
  if (tid < 16){ sB0[tid] = b0[mem*16 + tid]; sB1[tid] = b1[mem*16 + tid]; }
  __syncthreads();
  // stage emb(0) into sE buf0
  for (int i = tid; i < 16*E; i += 128){
    int r = i / E, e = i - r*E;
    float v  = emb[sTok[r][0]*E + e];
    short hi = f2bf(v);
    short lo = f2bf(v - bf2f(hi));
    sE[0][0][r][e] = hi; sE[0][1][r][e] = lo;
  }
  __syncthreads();

  auto poll = [&](int target){
    if (tid == 0){ while (LOAD_RLX(cnt) < target) {} }
  };
  // 16-MFMA GEMM: A-fragments direct from XCD-L2 hi/lo planes (sc0 dwordx4),
  // B from stationary sW[wb]/sW[wb+1].
  auto gemm16 = [&](const short* aHi, const short* aLo, int wb,
                    f32x4& za, f32x4& zb, f32x4& zc, f32x4& zd){
    const short* ph = aHi + (cl*16 + m)*U + q*8;
    const short* pl = aLo + (cl*16 + m)*U + q*8;
    #pragma unroll
    for (int g = 0; g < 4; ++g){
      U16x8 rh[4], rl[4];
      #pragma unroll
      for (int u = 0; u < 4; ++u){
        L2LOADX4(rh[u].u, ph + (4*g+u)*32);
        L2LOADX4(rl[u].u, pl + (4*g+u)*32);
      }
      WAIT_VM0();
      #pragma unroll
      for (int u = 0; u < 4; ++u){
        int kk = 4*g + u;
        short8 bh = *(const short8*)&sW[wb  ][m][kk*32 + q*8];
        short8 bl = *(const short8*)&sW[wb+1][m][kk*32 + q*8];
        za = MFMA16(rh[u].s, bh, za); zb = MFMA16(rl[u].s, bh, zb);
        zc = MFMA16(rh[u].s, bl, zc); zd = MFMA16(rl[u].s, bl, zd);
      }
    }
  };

  const f32x4 zero4 = {0.f, 0.f, 0.f, 0.f};

  // ---------------- recurrence ----------------
  // counter: +64/step (wave0 lane0 + wave1 lane0 per block).
  // targets: 64t = step-t start (all h1(t-1) posted); 64t+32 = h0(t) ready.
  for (int t = 0; t < T; ++t){
    if (t > 0){ poll(64*t); }
    __syncthreads();                       // release both waves; h(t-1) visible

    // ---- round A compute (both waves read h(t-1) planes)
    f32x4 z1a = zero4, z1b = zero4, z1c = zero4, z1d = zero4;  // wave1: h@rk1
    f32x4 z = zero4;
    if (w == 0){
      f32x4 za = zero4, zb = zero4, zc = zero4, zd = zero4;
      const int eb = t & 1;
      #pragma unroll
      for (int kk = 0; kk < 4; ++kk){      // x@k0 (LDS both sides)
        short8 ah = *(const short8*)&sE[eb][0][m][kk*32 + q*8];
        short8 al = *(const short8*)&sE[eb][1][m][kk*32 + q*8];
        short8 bh = *(const short8*)&sK0[0][m][kk*32 + q*8];
        short8 bl = *(const short8*)&sK0[1][m][kk*32 + q*8];
        za = MFMA16(ah, bh, za); zb = MFMA16(al, bh, zb);
        zc = MFMA16(ah, bl, zc); zd = MFMA16(al, bl, zd);
      }
      if (t > 0) gemm16(hHi, hLo, 0, za, zb, zc, zd);   // h@rk0
      z = za; z += zb; z += zc; z += zd;
      #pragma unroll
      for (int r = 0; r < 4; ++r){         // store h0(t) -> XCD L2 (pre-barrier drain)
        float h0v = fast_tanh(z[r] + sB0[m]);
        short hi = f2bf(h0v);
        short lo = f2bf(h0v - bf2f(hi));
        int idx = (cl*16 + q*4 + r)*U + mem*16 + m;
        h0Hi[idx] = hi; h0Lo[idx] = lo;
      }
    } else {
      if (t > 0) gemm16(hHi, hLo, 2, z1a, z1b, z1c, z1d);  // h@rk1
    }
    __syncthreads();   // certifies ALL rk0/rk1 reads of h(t-1) done (race guard)
    if (w == 0){
      WAIT_VM0();                          // own h0 stores in L2
      if (lane == 0) ADD_RLX(cnt, 1);      // counter -> 64t+32 when all wave0s in
    }

    // ---- round B: h1 = tanh(h0@k1 + h@rk1 + b1)
    poll(64*t + 32);
    __syncthreads();
    if (w == 1){
      f32x4 za = zero4, zb = zero4, zc = zero4, zd = zero4;
      gemm16(h0Hi, h0Lo, 4, za, zb, zc, zd);               // h0@k1
      f32x4 zz = za; zz += zb; zz += zc; zz += zd;
      zz += z1a; zz += z1b; zz += z1c; zz += z1d;
      #pragma unroll
      for (int r = 0; r < 4; ++r){
        float h1v = fast_tanh(zz[r] + sB1[m]);
        short hi = f2bf(h1v);
        short lo = f2bf(h1v - bf2f(hi));
        int idx = (cl*16 + q*4 + r)*U + mem*16 + m;
        hHi[idx] = hi; hLo[idx] = lo;      // plain stores -> XCD L2
      }
      WAIT_VM0();
      if (lane == 0) ADD_RLX(cnt, 1);      // counter -> 64(t+1) when all in
    } else if (t + 1 < T){
      // wave0: prefetch emb(t+1) into dbuf (self-consumed; overlaps wave1 gemm)
      const int nb = (t + 1) & 1;
      for (int i = lane; i < 16*E; i += 64){
        int r = i / E, e = i - r*E;
        float v  = emb[sTok[r][t+1]*E + e];
        short hi = f2bf(v);
        short lo = f2bf(v - bf2f(hi));
        sE[nb][0][r][e] = hi; sE[nb][1][r][e] = lo;
      }
    }
    // loop-top poll+barrier re-aligns waves
  }

  // ---------------- epilogue: logits = h@wd + bd ; sigmoid ----------------
  if (mem == 0){
    poll(64*T);
    __syncthreads();
    {
      int row = tid >> 3, seg = tid & 7;
      const short* ph = hHi + (cl*16 + row)*U + seg*64;
      const short* pl = hLo + (cl*16 + row)*U + seg*64;
      float acc = 0.f;
      #pragma unroll
      for (int j = 0; j < 8; ++j){
        U16x8 rh, rl;
        L2LOADX4(rh.u, ph + j*8);
        L2LOADX4(rl.u, pl + j*8);
        WAIT_VM0();
        #pragma unroll
        for (int e = 0; e < 8; ++e)
          acc += (bf2f(rh.s[e]) + bf2f(rl.s[e])) * wd[seg*64 + j*8 + e];
      }
      sRed[row][seg] = acc;
    }
    __syncthreads();
    if (tid < 16){
      float s = bd[0];
      #pragma unroll
      for (int j = 0; j < 8; ++j) s += sRed[tid][j];
      out[cl*16 + tid] = 1.f / (1.f + __expf(-s));
    }
  }

  // replay hygiene (R7-proven): write back dirty L2 exchange/counter lines
  __threadfence();
}

extern "C" void kernel_launch(void* const* d_in, const int* in_sizes, int n_in,
                              void* d_out, int out_size, void* d_ws, size_t ws_size,
                              hipStream_t stream) {
  const int*   tokens = (const int*)  d_in[0];
  const float* emb    = (const float*)d_in[1];
  const float* k0     = (const float*)d_in[2];
  const float* rk0    = (const float*)d_in[3];
  const float* b0     = (const float*)d_in[4];
  const float* k1     = (const float*)d_in[5];
  const float* rk1    = (const float*)d_in[6];
  const float* b1     = (const float*)d_in[7];
  const float* wd     = (const float*)d_in[8];
  const float* bd     = (const float*)d_in[9];

  // Zero sync + registration counters (0xAA poison breaks monotonic arith).
  hipMemsetAsync(d_ws, 0, 4096, stream);

  hipLaunchKernelGGL(rnn_kernel, dim3(256), dim3(128), 0, stream,
                     tokens, emb, k0, rk0, b0, k1, rk1, b1, wd, bd,
                     (float*)d_out, (char*)d_ws);
}